// Round 3
// baseline (593.786 us; speedup 1.0000x reference)
//
#include <hip/hip_runtime.h>
#include <math.h>

#define B_ 16
#define C_ 3
#define H_ 320
#define W_ 448
#define HW_ (H_*W_)
#define NITERS_ 5
#define LAMBDA_ 0.01f
#define HUBER_ 0.1f
#define EPS_ 1e-6f

#define BPB 112       // blocks per batch (1792 total)
#define CHUNK 1280    // pixels per block == 5*TPB exactly; 112*1280 == H*W
#define TPB 256
#define PPT 5         // pixels per thread (CHUNK/TPB), static

// ---------------- SE(3) exp in double ----------------
__device__ __host__ inline void se3_exp_d(const double xi[6], double T[16]) {
    double vx = xi[0], vy = xi[1], vz = xi[2];
    double wx = xi[3], wy = xi[4], wz = xi[5];
    double th2  = wx*wx + wy*wy + wz*wz;
    double th2c = th2 > 1e-16 ? th2 : 1e-16;
    double th   = sqrt(th2c);
    bool   sm   = th2 < 1e-10;
    double A  = sm ? (1.0 - th2*(1.0/6.0))   : (sin(th)/th);
    double Bc = sm ? (0.5 - th2*(1.0/24.0))  : ((1.0 - cos(th))/th2c);
    double Cc = sm ? (1.0/6.0 - th2*(1.0/120.0)) : ((1.0 - A)/th2c);
    double K[9]  = {0.0,-wz,wy,  wz,0.0,-wx,  -wy,wx,0.0};
    double K2[9];
    #pragma unroll
    for (int i = 0; i < 3; ++i)
        #pragma unroll
        for (int j = 0; j < 3; ++j) {
            double s = 0.0;
            #pragma unroll
            for (int k = 0; k < 3; ++k) s += K[i*3+k]*K[k*3+j];
            K2[i*3+j] = s;
        }
    double R[9], V[9];
    #pragma unroll
    for (int i = 0; i < 9; ++i) {
        double I = (i == 0 || i == 4 || i == 8) ? 1.0 : 0.0;
        R[i] = I + A*K[i]  + Bc*K2[i];
        V[i] = I + Bc*K[i] + Cc*K2[i];
    }
    double tx = V[0]*vx + V[1]*vy + V[2]*vz;
    double ty = V[3]*vx + V[4]*vy + V[5]*vz;
    double tz = V[6]*vx + V[7]*vy + V[8]*vz;
    T[0]=R[0]; T[1]=R[1]; T[2] =R[2]; T[3] =tx;
    T[4]=R[3]; T[5]=R[4]; T[6] =R[5]; T[7] =ty;
    T[8]=R[6]; T[9]=R[7]; T[10]=R[8]; T[11]=tz;
    T[12]=0.0; T[13]=0.0; T[14]=0.0;  T[15]=1.0;
}

// ---------------- init: T = se3_exp(pose_twist) ----------------
__global__ void init_kernel(const float* __restrict__ pose,
                            float* __restrict__ Tcur, float* __restrict__ Tinit) {
    int b = threadIdx.x;
    if (b >= B_) return;
    double xi[6];
    #pragma unroll
    for (int k = 0; k < 6; ++k) xi[k] = (double)pose[b*6+k];
    double T[16];
    se3_exp_d(xi, T);
    #pragma unroll
    for (int k = 0; k < 16; ++k) {
        float f = (float)T[k];
        Tcur[b*16+k]  = f;
        Tinit[b*16+k] = f;
    }
}

// ---------------- per-pixel GN accumulation ----------------
__global__ __launch_bounds__(TPB, 4)
void pixel_kernel(const float* __restrict__ I0, const float* __restrict__ I1,
                  const float* __restrict__ invD0, const float* __restrict__ invD1,
                  const float* __restrict__ intr,
                  const float* __restrict__ Tcur, const float* __restrict__ Tinit,
                  float* __restrict__ partials)
{
    // XCD-aware swizzle: hardware round-robins blockIdx across 8 XCDs.
    // Map so each XCD gets 224 CONSECUTIVE chunks (contiguous image memory,
    // shared stencil rows -> L2 hits). Bijective: 1792 % 8 == 0.
    const int nwg = B_*BPB;
    const int bid = blockIdx.x;
    const int swz = (bid & 7) * (nwg >> 3) + (bid >> 3);
    const int b   = swz / BPB;
    const int blk = swz % BPB;

    const float fx = intr[b*4+0], fy = intr[b*4+1];
    const float cx = intr[b*4+2], cy = intr[b*4+3];

    const float* Tc = Tcur  + b*16;
    const float* Ti = Tinit + b*16;
    const float Rc00=Tc[0], Rc01=Tc[1], Rc02=Tc[2],  tcx=Tc[3];
    const float Rc10=Tc[4], Rc11=Tc[5], Rc12=Tc[6],  tcy=Tc[7];
    const float Rc20=Tc[8], Rc21=Tc[9], Rc22=Tc[10], tcz=Tc[11];
    const float Ri00=Ti[0], Ri01=Ti[1], Ri02=Ti[2],  tix=Ti[3];
    const float Ri10=Ti[4], Ri11=Ti[5], Ri12=Ti[6],  tiy=Ti[7];
    const float Ri20=Ti[8], Ri21=Ti[9], Ri22=Ti[10], tiz=Ti[11];

    const float* P0 = I0    + (size_t)b*C_*HW_;
    const float* P1 = I1    + (size_t)b*C_*HW_;
    const float* D0 = invD0 + (size_t)b*HW_;
    const float* D1 = invD1 + (size_t)b*HW_;

    float acc[27];
    #pragma unroll
    for (int k = 0; k < 27; ++k) acc[k] = 0.0f;

    const int base = blk*CHUNK + (int)threadIdx.x;

    auto body = [&](int p) {
        const int vcoord = p / W_;
        const int ucoord = p - vcoord*W_;

        // back-project with invD1
        const float iD1 = D1[p];
        const float iD  = fmaxf(iD1, EPS_);
        const float z1  = 1.0f / iD;
        const float x1  = ((float)ucoord - cx)/fx * z1;
        const float y1  = ((float)vcoord - cy)/fy * z1;

        // current warp
        const float Xc0 = Rc00*x1 + Rc01*y1 + Rc02*z1 + tcx;
        const float Xc1 = Rc10*x1 + Rc11*y1 + Rc12*z1 + tcy;
        const float Xc2 = Rc20*x1 + Rc21*y1 + Rc22*z1 + tcz;
        const float z0s = (fabsf(Xc2) > EPS_) ? Xc2 : EPS_;
        const float izc = 1.0f / z0s;
        const float u0  = fx*Xc0*izc + cx;
        const float v0  = fy*Xc1*izc + cy;
        const bool valid = (Xc2 > EPS_) && (iD1 > EPS_);
        const bool inb   = (u0 > 0.0f) && (u0 < (float)(W_-1)) &&
                           (v0 > 0.0f) && (v0 < (float)(H_-1));
        const bool vm = valid && inb;

        // initial-T projection for Jacobian (fixed linearization point)
        const float Xi0 = Ri00*x1 + Ri01*y1 + Ri02*z1 + tix;
        const float Xi1 = Ri10*x1 + Ri11*y1 + Ri12*z1 + tiy;
        const float Xi2 = Ri20*x1 + Ri21*y1 + Ri22*z1 + tiz;
        const float zis = (fabsf(Xi2) > EPS_) ? Xi2 : EPS_;
        const float izi = 1.0f / zis;
        const float aJ = fx*izi;
        const float cJ = -fx*Xi0*izi*izi;
        const float bJ = fy*izi;
        const float dJ = -fy*Xi1*izi*izi;
        const float Jw0[6] = {aJ, 0.0f, cJ, cJ*Xi1, aJ*Xi2 - cJ*Xi0, -aJ*Xi1};
        const float Jw1[6] = {0.0f, bJ, dJ, dJ*Xi1 - bJ*Xi2, -dJ*Xi0, bJ*Xi0};
        const float Jtz[6] = {0.0f, 0.0f, 1.0f, Xi1, -Xi0, 0.0f};

        // normalized grid (clipped), back to pixel coords -- mirror reference ops
        const float gx = fminf(fmaxf((u0/(float)(W_-1) - 0.5f)*2.0f, -2.0f), 2.0f);
        const float gy = fminf(fmaxf((v0/(float)(H_-1) - 0.5f)*2.0f, -2.0f), 2.0f);
        const float ix = (gx + 1.0f)*0.5f*(float)(W_-1);
        const float iy = (gy + 1.0f)*0.5f*(float)(H_-1);
        const float x0f = floorf(ix), y0f = floorf(iy);
        const float wx1 = ix - x0f,  wy1 = iy - y0f;
        const float wx0 = 1.0f - wx1, wy0 = 1.0f - wy1;
        const float w00 = wx0*wy0, w10 = wx1*wy0, w01 = wx0*wy1, w11 = wx1*wy1;

        float sI[3], sgxI[3], sgyI[3];
        float sD, sgxD, sgyD;

        // interior fast path: all taps AND all gradient stencil points unclamped
        const bool fast = (x0f >= 1.0f) && (x0f <= (float)(W_-3)) &&
                          (y0f >= 1.0f) && (y0f <= (float)(H_-3));

        if (__all((int)fast)) {
            const int xi0 = (int)x0f;
            const int yi0 = (int)y0f;
            const int off = yi0*W_ + xi0;
            #pragma unroll
            for (int c = 0; c < 4; ++c) {
                const float* pr = (c < 3 ? P0 + c*HW_ : D0) + off;
                // 12 unique loads covering value/dx/dy of all 4 taps
                const float am0 = pr[-1],    v00 = pr[0],     v10 = pr[1],     ap0 = pr[2];
                const float am1 = pr[W_-1],  v01 = pr[W_],    v11 = pr[W_+1],  ap1 = pr[W_+2];
                const float um0 = pr[-W_],   um1 = pr[-W_+1];
                const float dm0 = pr[2*W_],  dm1 = pr[2*W_+1];
                const float dx00 = 0.5f*(v10 - am0);
                const float dx10 = 0.5f*(ap0 - v00);
                const float dx01 = 0.5f*(v11 - am1);
                const float dx11 = 0.5f*(ap1 - v01);
                const float dy00 = 0.5f*(v01 - um0);
                const float dy10 = 0.5f*(v11 - um1);
                const float dy01 = 0.5f*(dm0 - v00);
                const float dy11 = 0.5f*(dm1 - v10);
                const float sv = w00*v00  + w10*v10  + w01*v01  + w11*v11;
                const float sx = w00*dx00 + w10*dx10 + w01*dx01 + w11*dx11;
                const float sy = w00*dy00 + w10*dy10 + w01*dy01 + w11*dy11;
                if (c < 3) { sI[c] = sv; sgxI[c] = sx; sgyI[c] = sy; }
                else       { sD    = sv; sgxD    = sx; sgyD    = sy; }
            }
        } else {
            float tI[3]  = {0,0,0}, tgx[3] = {0,0,0}, tgy[3] = {0,0,0};
            float tD = 0.0f, tgxD = 0.0f, tgyD = 0.0f;
            #pragma unroll
            for (int tap = 0; tap < 4; ++tap) {
                const float xf = x0f + (float)(tap & 1);
                const float yf = y0f + (float)(tap >> 1);
                const float wgt = ((tap & 1) ? wx1 : wx0) * ((tap >> 1) ? wy1 : wy0);
                const float m = (xf >= 0.0f && xf <= (float)(W_-1) &&
                                 yf >= 0.0f && yf <= (float)(H_-1)) ? wgt : 0.0f;
                int xc = (int)xf; xc = xc < 0 ? 0 : (xc > W_-1 ? W_-1 : xc);
                int yc = (int)yf; yc = yc < 0 ? 0 : (yc > H_-1 ? H_-1 : yc);
                const int xp = (xc+1 > W_-1) ? W_-1 : xc+1;
                const int xm = (xc-1 < 0) ? 0 : xc-1;
                const int row  = yc*W_;
                const int rowp = ((yc+1 > H_-1) ? H_-1 : yc+1)*W_;
                const int rowm = ((yc-1 < 0) ? 0 : yc-1)*W_;
                #pragma unroll
                for (int c = 0; c < 3; ++c) {
                    const float* pc = P0 + c*HW_;
                    tI[c]  += m * pc[row+xc];
                    tgx[c] += m * 0.5f*(pc[row+xp]  - pc[row+xm]);
                    tgy[c] += m * 0.5f*(pc[rowp+xc] - pc[rowm+xc]);
                }
                tD   += m * D0[row+xc];
                tgxD += m * 0.5f*(D0[row+xp]  - D0[row+xm]);
                tgyD += m * 0.5f*(D0[rowp+xc] - D0[rowm+xc]);
            }
            #pragma unroll
            for (int c = 0; c < 3; ++c) { sI[c] = tI[c]; sgxI[c] = tgx[c]; sgyI[c] = tgy[c]; }
            sD = tD; sgxD = tgxD; sgyD = tgyD;
        }

        // photometric channels
        #pragma unroll
        for (int c = 0; c < 3; ++c) {
            const float r = vm ? (P1[c*HW_ + p] - sI[c]) : 1e-6f;
            const float w = fminf(1.0f, HUBER_ / fmaxf(fabsf(r), EPS_));
            float J[6];
            #pragma unroll
            for (int k = 0; k < 6; ++k)
                J[k] = -(sgxI[c]*Jw0[k] + sgyI[c]*Jw1[k]);
            const float wr = w*r;
            int idx = 0;
            #pragma unroll
            for (int i2 = 0; i2 < 6; ++i2) {
                const float wJi = w*J[i2];
                #pragma unroll
                for (int j2 = i2; j2 < 6; ++j2)
                    acc[idx++] += wJi*J[j2];
                acc[21+i2] += wr*J[i2];
            }
        }
        // depth channel (scaled by LAMBDA)
        {
            const float rz = LAMBDA_ * (vm ? (izc - sD) : 1e-6f);
            const float w  = fminf(1.0f, HUBER_ / fmaxf(fabsf(rz), EPS_));
            float J[6];
            #pragma unroll
            for (int k = 0; k < 6; ++k)
                J[k] = LAMBDA_ * (Jtz[k] - (sgxD*Jw0[k] + sgyD*Jw1[k]));
            const float wr = w*rz;
            int idx = 0;
            #pragma unroll
            for (int i2 = 0; i2 < 6; ++i2) {
                const float wJi = w*J[i2];
                #pragma unroll
                for (int j2 = i2; j2 < 6; ++j2)
                    acc[idx++] += wJi*J[j2];
                acc[21+i2] += wr*J[i2];
            }
        }
    };

    // static trip count -> full unroll -> 5 pixels of loads in flight per wave
    #pragma unroll
    for (int i5 = 0; i5 < PPT; ++i5)
        body(base + i5*TPB);

    // wave (64-lane) reduction in float
    #pragma unroll
    for (int off = 32; off >= 1; off >>= 1) {
        #pragma unroll
        for (int k = 0; k < 27; ++k)
            acc[k] += __shfl_down(acc[k], off);
    }
    __shared__ float red[TPB/64][27];
    const int lane = threadIdx.x & 63;
    const int wid  = threadIdx.x >> 6;
    if (lane == 0) {
        #pragma unroll
        for (int k = 0; k < 27; ++k) red[wid][k] = acc[k];
    }
    __syncthreads();
    if (threadIdx.x < 27) {
        float s = red[0][threadIdx.x] + red[1][threadIdx.x]
                + red[2][threadIdx.x] + red[3][threadIdx.x];
        partials[((size_t)b*BPB + blk)*27 + threadIdx.x] = s;
    }
}

// ---------------- reduce partials, solve 6x6, update T ----------------
__global__ void solve_kernel(const float* __restrict__ partials,
                             float* __restrict__ Tcur, float* __restrict__ out)
{
    const int b = blockIdx.x;
    __shared__ double S[27];
    const int t = threadIdx.x;
    if (t < 27) {
        double s = 0.0;
        const float* pp = partials + (size_t)b*BPB*27 + t;
        for (int blk = 0; blk < BPB; ++blk) s += (double)pp[blk*27];
        S[t] = s;
    }
    __syncthreads();
    if (t == 0) {
        double Hm[6][6], rhs[6];
        int idx = 0;
        for (int i = 0; i < 6; ++i)
            for (int j = i; j < 6; ++j) { Hm[i][j] = S[idx]; Hm[j][i] = S[idx]; ++idx; }
        double tr = 0.0;
        for (int i = 0; i < 6; ++i) tr += Hm[i][i];
        const double damp = tr*1e-6;
        for (int i = 0; i < 6; ++i) Hm[i][i] += damp;
        for (int i = 0; i < 6; ++i) rhs[i] = S[21+i];

        // Gaussian elimination with partial pivoting
        double M[6][7];
        for (int i = 0; i < 6; ++i) {
            for (int j = 0; j < 6; ++j) M[i][j] = Hm[i][j];
            M[i][6] = rhs[i];
        }
        for (int col = 0; col < 6; ++col) {
            int piv = col; double mx = fabs(M[col][col]);
            for (int r2 = col+1; r2 < 6; ++r2) {
                double a2 = fabs(M[r2][col]);
                if (a2 > mx) { mx = a2; piv = r2; }
            }
            if (piv != col)
                for (int j = col; j < 7; ++j) {
                    double tmp = M[col][j]; M[col][j] = M[piv][j]; M[piv][j] = tmp;
                }
            const double inv = 1.0 / M[col][col];
            for (int r2 = col+1; r2 < 6; ++r2) {
                const double f = M[r2][col]*inv;
                for (int j = col; j < 7; ++j) M[r2][j] -= f*M[col][j];
            }
        }
        double xi[6];
        for (int i = 5; i >= 0; --i) {
            double s2 = M[i][6];
            for (int j = i+1; j < 6; ++j) s2 -= M[i][j]*xi[j];
            xi[i] = s2 / M[i][i];
        }
        double nxi[6];
        for (int i = 0; i < 6; ++i) nxi[i] = -xi[i];
        double E[16];
        se3_exp_d(nxi, E);

        double Tc[16];
        for (int k = 0; k < 16; ++k) Tc[k] = (double)Tcur[b*16+k];
        for (int i = 0; i < 4; ++i)
            for (int j = 0; j < 4; ++j) {
                double s2 = 0.0;
                for (int k = 0; k < 4; ++k) s2 += Tc[i*4+k]*E[k*4+j];
                const float f = (float)s2;
                Tcur[b*16 + i*4 + j] = f;
                out[b*16 + i*4 + j]  = f;
            }
    }
}

extern "C" void kernel_launch(void* const* d_in, const int* in_sizes, int n_in,
                              void* d_out, int out_size, void* d_ws, size_t ws_size,
                              hipStream_t stream) {
    const float* pose  = (const float*)d_in[0];
    const float* I0    = (const float*)d_in[1];
    const float* I1    = (const float*)d_in[2];
    const float* invD0 = (const float*)d_in[3];
    const float* invD1 = (const float*)d_in[4];
    const float* intr  = (const float*)d_in[5];
    float* out = (float*)d_out;

    float* Tcur     = (float*)d_ws;
    float* Tinit    = Tcur + 256;
    float* partials = (float*)((char*)d_ws + 2048);  // 16*112*27 floats ~ 189 KiB

    hipLaunchKernelGGL(init_kernel, dim3(1), dim3(64), 0, stream, pose, Tcur, Tinit);
    for (int it = 0; it < NITERS_; ++it) {
        hipLaunchKernelGGL(pixel_kernel, dim3(B_*BPB), dim3(TPB), 0, stream,
                           I0, I1, invD0, invD1, intr, Tcur, Tinit, partials);
        hipLaunchKernelGGL(solve_kernel, dim3(B_), dim3(64), 0, stream,
                           partials, Tcur, out);
    }
}

// Round 4
// 453.931 us; speedup vs baseline: 1.3081x; 1.3081x over previous
//
#include <hip/hip_runtime.h>
#include <math.h>

#define B_ 16
#define C_ 3
#define H_ 320
#define W_ 448
#define HW_ (H_*W_)
#define NITERS_ 5
#define LAMBDA_ 0.01f
#define HUBER_ 0.1f
#define EPS_ 1e-6f

#define BPB 112       // blocks per batch (1792 total)
#define CHUNK 1280    // pixels per block == 5*TPB exactly; 112*1280 == H*W
#define TPB 256
#define PPT 5         // pixels per thread (CHUNK/TPB), static

// ---------------- SE(3) exp in double ----------------
__device__ __host__ inline void se3_exp_d(const double xi[6], double T[16]) {
    double vx = xi[0], vy = xi[1], vz = xi[2];
    double wx = xi[3], wy = xi[4], wz = xi[5];
    double th2  = wx*wx + wy*wy + wz*wz;
    double th2c = th2 > 1e-16 ? th2 : 1e-16;
    double th   = sqrt(th2c);
    bool   sm   = th2 < 1e-10;
    double A  = sm ? (1.0 - th2*(1.0/6.0))   : (sin(th)/th);
    double Bc = sm ? (0.5 - th2*(1.0/24.0))  : ((1.0 - cos(th))/th2c);
    double Cc = sm ? (1.0/6.0 - th2*(1.0/120.0)) : ((1.0 - A)/th2c);
    double K[9]  = {0.0,-wz,wy,  wz,0.0,-wx,  -wy,wx,0.0};
    double K2[9];
    #pragma unroll
    for (int i = 0; i < 3; ++i)
        #pragma unroll
        for (int j = 0; j < 3; ++j) {
            double s = 0.0;
            #pragma unroll
            for (int k = 0; k < 3; ++k) s += K[i*3+k]*K[k*3+j];
            K2[i*3+j] = s;
        }
    double R[9], V[9];
    #pragma unroll
    for (int i = 0; i < 9; ++i) {
        double I = (i == 0 || i == 4 || i == 8) ? 1.0 : 0.0;
        R[i] = I + A*K[i]  + Bc*K2[i];
        V[i] = I + Bc*K[i] + Cc*K2[i];
    }
    double tx = V[0]*vx + V[1]*vy + V[2]*vz;
    double ty = V[3]*vx + V[4]*vy + V[5]*vz;
    double tz = V[6]*vx + V[7]*vy + V[8]*vz;
    T[0]=R[0]; T[1]=R[1]; T[2] =R[2]; T[3] =tx;
    T[4]=R[3]; T[5]=R[4]; T[6] =R[5]; T[7] =ty;
    T[8]=R[6]; T[9]=R[7]; T[10]=R[8]; T[11]=tz;
    T[12]=0.0; T[13]=0.0; T[14]=0.0;  T[15]=1.0;
}

// ---------------- init: T = se3_exp(pose_twist) ----------------
__global__ void init_kernel(const float* __restrict__ pose,
                            float* __restrict__ Tcur, float* __restrict__ Tinit) {
    int b = threadIdx.x;
    if (b >= B_) return;
    double xi[6];
    #pragma unroll
    for (int k = 0; k < 6; ++k) xi[k] = (double)pose[b*6+k];
    double T[16];
    se3_exp_d(xi, T);
    #pragma unroll
    for (int k = 0; k < 16; ++k) {
        float f = (float)T[k];
        Tcur[b*16+k]  = f;
        Tinit[b*16+k] = f;
    }
}

// ---------------- per-pixel GN accumulation ----------------
// NOTE: no min-waves arg -- (256,4)/(256,5) forced VGPR 48-64 + ~100MB/dispatch
// scratch spill traffic (R2/R3 WRITE_SIZE evidence). Natural alloc (R1) was clean.
__global__ __launch_bounds__(TPB)
void pixel_kernel(const float* __restrict__ I0, const float* __restrict__ I1,
                  const float* __restrict__ invD0, const float* __restrict__ invD1,
                  const float* __restrict__ intr,
                  const float* __restrict__ Tcur, const float* __restrict__ Tinit,
                  float* __restrict__ partials)
{
    // XCD-aware swizzle: each XCD gets contiguous chunks (L2 locality).
    // Bijective: 1792 % 8 == 0.  (R3: FETCH 193 -> 114 MB)
    const int nwg = B_*BPB;
    const int bid = blockIdx.x;
    const int swz = (bid & 7) * (nwg >> 3) + (bid >> 3);
    const int b   = swz / BPB;
    const int blk = swz % BPB;

    const float fx = intr[b*4+0], fy = intr[b*4+1];
    const float cx = intr[b*4+2], cy = intr[b*4+3];
    const float inv_fx = 1.0f/fx, inv_fy = 1.0f/fy;

    const float* Tc = Tcur  + b*16;
    const float* Ti = Tinit + b*16;
    const float Rc00=Tc[0], Rc01=Tc[1], Rc02=Tc[2],  tcx=Tc[3];
    const float Rc10=Tc[4], Rc11=Tc[5], Rc12=Tc[6],  tcy=Tc[7];
    const float Rc20=Tc[8], Rc21=Tc[9], Rc22=Tc[10], tcz=Tc[11];
    const float Ri00=Ti[0], Ri01=Ti[1], Ri02=Ti[2],  tix=Ti[3];
    const float Ri10=Ti[4], Ri11=Ti[5], Ri12=Ti[6],  tiy=Ti[7];
    const float Ri20=Ti[8], Ri21=Ti[9], Ri22=Ti[10], tiz=Ti[11];

    const float* P0 = I0    + (size_t)b*C_*HW_;
    const float* P1 = I1    + (size_t)b*C_*HW_;
    const float* D0 = invD0 + (size_t)b*HW_;
    const float* D1 = invD1 + (size_t)b*HW_;

    float acc[27];
    #pragma unroll
    for (int k = 0; k < 27; ++k) acc[k] = 0.0f;

    const int base = blk*CHUNK + (int)threadIdx.x;

    // ---- up-front preload of all linear-address data (20 independent
    // coalesced loads in flight before any compute) ----
    float d1v[PPT];
    float p1v[C_][PPT];
    #pragma unroll
    for (int i = 0; i < PPT; ++i) d1v[i] = D1[base + i*TPB];
    #pragma unroll
    for (int c = 0; c < C_; ++c)
        #pragma unroll
        for (int i = 0; i < PPT; ++i) p1v[c][i] = P1[c*HW_ + base + i*TPB];

    auto body = [&](int i5) {
        const int p = base + i5*TPB;
        const int vcoord = p / W_;
        const int ucoord = p - vcoord*W_;

        // back-project with invD1 (preloaded)
        const float iD1 = d1v[i5];
        const float iD  = fmaxf(iD1, EPS_);
        const float z1  = 1.0f / iD;
        const float x1  = ((float)ucoord - cx)*inv_fx * z1;
        const float y1  = ((float)vcoord - cy)*inv_fy * z1;

        // current warp
        const float Xc0 = Rc00*x1 + Rc01*y1 + Rc02*z1 + tcx;
        const float Xc1 = Rc10*x1 + Rc11*y1 + Rc12*z1 + tcy;
        const float Xc2 = Rc20*x1 + Rc21*y1 + Rc22*z1 + tcz;
        const float z0s = (fabsf(Xc2) > EPS_) ? Xc2 : EPS_;
        const float izc = 1.0f / z0s;
        const float u0  = fx*Xc0*izc + cx;
        const float v0  = fy*Xc1*izc + cy;
        const bool valid = (Xc2 > EPS_) && (iD1 > EPS_);
        const bool inb   = (u0 > 0.0f) && (u0 < (float)(W_-1)) &&
                           (v0 > 0.0f) && (v0 < (float)(H_-1));
        const bool vm = valid && inb;

        // initial-T projection for Jacobian (fixed linearization point)
        const float Xi0 = Ri00*x1 + Ri01*y1 + Ri02*z1 + tix;
        const float Xi1 = Ri10*x1 + Ri11*y1 + Ri12*z1 + tiy;
        const float Xi2 = Ri20*x1 + Ri21*y1 + Ri22*z1 + tiz;
        const float zis = (fabsf(Xi2) > EPS_) ? Xi2 : EPS_;
        const float izi = 1.0f / zis;
        const float aJ = fx*izi;
        const float cJ = -fx*Xi0*izi*izi;
        const float bJ = fy*izi;
        const float dJ = -fy*Xi1*izi*izi;
        const float Jw0[6] = {aJ, 0.0f, cJ, cJ*Xi1, aJ*Xi2 - cJ*Xi0, -aJ*Xi1};
        const float Jw1[6] = {0.0f, bJ, dJ, dJ*Xi1 - bJ*Xi2, -dJ*Xi0, bJ*Xi0};
        const float Jtz[6] = {0.0f, 0.0f, 1.0f, Xi1, -Xi0, 0.0f};

        // normalized grid (clipped), back to pixel coords -- mirror reference ops
        const float gx = fminf(fmaxf((u0/(float)(W_-1) - 0.5f)*2.0f, -2.0f), 2.0f);
        const float gy = fminf(fmaxf((v0/(float)(H_-1) - 0.5f)*2.0f, -2.0f), 2.0f);
        const float ix = (gx + 1.0f)*0.5f*(float)(W_-1);
        const float iy = (gy + 1.0f)*0.5f*(float)(H_-1);
        const float x0f = floorf(ix), y0f = floorf(iy);
        const float wx1 = ix - x0f,  wy1 = iy - y0f;
        const float wx0 = 1.0f - wx1, wy0 = 1.0f - wy1;
        const float w00 = wx0*wy0, w10 = wx1*wy0, w01 = wx0*wy1, w11 = wx1*wy1;

        float sI[3], sgxI[3], sgyI[3];
        float sD, sgxD, sgyD;

        // interior fast path: all taps AND all gradient stencil points unclamped
        const bool fast = (x0f >= 1.0f) && (x0f <= (float)(W_-3)) &&
                          (y0f >= 1.0f) && (y0f <= (float)(H_-3));

        if (__all((int)fast)) {
            const int xi0 = (int)x0f;
            const int yi0 = (int)y0f;
            const int off = yi0*W_ + xi0;
            #pragma unroll
            for (int c = 0; c < 4; ++c) {
                const float* pr = (c < 3 ? P0 + c*HW_ : D0) + off;
                // 12 unique loads covering value/dx/dy of all 4 taps
                const float am0 = pr[-1],    v00 = pr[0],     v10 = pr[1],     ap0 = pr[2];
                const float am1 = pr[W_-1],  v01 = pr[W_],    v11 = pr[W_+1],  ap1 = pr[W_+2];
                const float um0 = pr[-W_],   um1 = pr[-W_+1];
                const float dm0 = pr[2*W_],  dm1 = pr[2*W_+1];
                const float dx00 = 0.5f*(v10 - am0);
                const float dx10 = 0.5f*(ap0 - v00);
                const float dx01 = 0.5f*(v11 - am1);
                const float dx11 = 0.5f*(ap1 - v01);
                const float dy00 = 0.5f*(v01 - um0);
                const float dy10 = 0.5f*(v11 - um1);
                const float dy01 = 0.5f*(dm0 - v00);
                const float dy11 = 0.5f*(dm1 - v10);
                const float sv = w00*v00  + w10*v10  + w01*v01  + w11*v11;
                const float sx = w00*dx00 + w10*dx10 + w01*dx01 + w11*dx11;
                const float sy = w00*dy00 + w10*dy10 + w01*dy01 + w11*dy11;
                if (c < 3) { sI[c] = sv; sgxI[c] = sx; sgyI[c] = sy; }
                else       { sD    = sv; sgxD    = sx; sgyD    = sy; }
            }
        } else {
            float tI[3]  = {0,0,0}, tgx[3] = {0,0,0}, tgy[3] = {0,0,0};
            float tD = 0.0f, tgxD = 0.0f, tgyD = 0.0f;
            #pragma unroll
            for (int tap = 0; tap < 4; ++tap) {
                const float xf = x0f + (float)(tap & 1);
                const float yf = y0f + (float)(tap >> 1);
                const float wgt = ((tap & 1) ? wx1 : wx0) * ((tap >> 1) ? wy1 : wy0);
                const float m = (xf >= 0.0f && xf <= (float)(W_-1) &&
                                 yf >= 0.0f && yf <= (float)(H_-1)) ? wgt : 0.0f;
                int xc = (int)xf; xc = xc < 0 ? 0 : (xc > W_-1 ? W_-1 : xc);
                int yc = (int)yf; yc = yc < 0 ? 0 : (yc > H_-1 ? H_-1 : yc);
                const int xp = (xc+1 > W_-1) ? W_-1 : xc+1;
                const int xm = (xc-1 < 0) ? 0 : xc-1;
                const int row  = yc*W_;
                const int rowp = ((yc+1 > H_-1) ? H_-1 : yc+1)*W_;
                const int rowm = ((yc-1 < 0) ? 0 : yc-1)*W_;
                #pragma unroll
                for (int c = 0; c < 3; ++c) {
                    const float* pc = P0 + c*HW_;
                    tI[c]  += m * pc[row+xc];
                    tgx[c] += m * 0.5f*(pc[row+xp]  - pc[row+xm]);
                    tgy[c] += m * 0.5f*(pc[rowp+xc] - pc[rowm+xc]);
                }
                tD   += m * D0[row+xc];
                tgxD += m * 0.5f*(D0[row+xp]  - D0[row+xm]);
                tgyD += m * 0.5f*(D0[rowp+xc] - D0[rowm+xc]);
            }
            #pragma unroll
            for (int c = 0; c < 3; ++c) { sI[c] = tI[c]; sgxI[c] = tgx[c]; sgyI[c] = tgy[c]; }
            sD = tD; sgxD = tgxD; sgyD = tgyD;
        }

        // photometric channels
        #pragma unroll
        for (int c = 0; c < 3; ++c) {
            const float r = vm ? (p1v[c][i5] - sI[c]) : 1e-6f;
            const float w = fminf(1.0f, HUBER_ / fmaxf(fabsf(r), EPS_));
            float J[6];
            #pragma unroll
            for (int k = 0; k < 6; ++k)
                J[k] = -(sgxI[c]*Jw0[k] + sgyI[c]*Jw1[k]);
            const float wr = w*r;
            int idx = 0;
            #pragma unroll
            for (int i2 = 0; i2 < 6; ++i2) {
                const float wJi = w*J[i2];
                #pragma unroll
                for (int j2 = i2; j2 < 6; ++j2)
                    acc[idx++] += wJi*J[j2];
                acc[21+i2] += wr*J[i2];
            }
        }
        // depth channel (scaled by LAMBDA)
        {
            const float rz = LAMBDA_ * (vm ? (izc - sD) : 1e-6f);
            const float w  = fminf(1.0f, HUBER_ / fmaxf(fabsf(rz), EPS_));
            float J[6];
            #pragma unroll
            for (int k = 0; k < 6; ++k)
                J[k] = LAMBDA_ * (Jtz[k] - (sgxD*Jw0[k] + sgyD*Jw1[k]));
            const float wr = w*rz;
            int idx = 0;
            #pragma unroll
            for (int i2 = 0; i2 < 6; ++i2) {
                const float wJi = w*J[i2];
                #pragma unroll
                for (int j2 = i2; j2 < 6; ++j2)
                    acc[idx++] += wJi*J[j2];
                acc[21+i2] += wr*J[i2];
            }
        }
    };

    #pragma unroll
    for (int i5 = 0; i5 < PPT; ++i5)
        body(i5);

    // wave (64-lane) reduction in float
    #pragma unroll
    for (int off = 32; off >= 1; off >>= 1) {
        #pragma unroll
        for (int k = 0; k < 27; ++k)
            acc[k] += __shfl_down(acc[k], off);
    }
    __shared__ float red[TPB/64][27];
    const int lane = threadIdx.x & 63;
    const int wid  = threadIdx.x >> 6;
    if (lane == 0) {
        #pragma unroll
        for (int k = 0; k < 27; ++k) red[wid][k] = acc[k];
    }
    __syncthreads();
    if (threadIdx.x < 27) {
        float s = red[0][threadIdx.x] + red[1][threadIdx.x]
                + red[2][threadIdx.x] + red[3][threadIdx.x];
        partials[((size_t)b*BPB + blk)*27 + threadIdx.x] = s;
    }
}

// ---------------- reduce partials, solve 6x6, update T ----------------
__global__ void solve_kernel(const float* __restrict__ partials,
                             float* __restrict__ Tcur, float* __restrict__ out)
{
    const int b = blockIdx.x;
    __shared__ double S[27];
    const int t = threadIdx.x;
    if (t < 27) {
        double s = 0.0;
        const float* pp = partials + (size_t)b*BPB*27 + t;
        for (int blk = 0; blk < BPB; ++blk) s += (double)pp[blk*27];
        S[t] = s;
    }
    __syncthreads();
    if (t == 0) {
        double Hm[6][6], rhs[6];
        int idx = 0;
        for (int i = 0; i < 6; ++i)
            for (int j = i; j < 6; ++j) { Hm[i][j] = S[idx]; Hm[j][i] = S[idx]; ++idx; }
        double tr = 0.0;
        for (int i = 0; i < 6; ++i) tr += Hm[i][i];
        const double damp = tr*1e-6;
        for (int i = 0; i < 6; ++i) Hm[i][i] += damp;
        for (int i = 0; i < 6; ++i) rhs[i] = S[21+i];

        // Gaussian elimination with partial pivoting
        double M[6][7];
        for (int i = 0; i < 6; ++i) {
            for (int j = 0; j < 6; ++j) M[i][j] = Hm[i][j];
            M[i][6] = rhs[i];
        }
        for (int col = 0; col < 6; ++col) {
            int piv = col; double mx = fabs(M[col][col]);
            for (int r2 = col+1; r2 < 6; ++r2) {
                double a2 = fabs(M[r2][col]);
                if (a2 > mx) { mx = a2; piv = r2; }
            }
            if (piv != col)
                for (int j = col; j < 7; ++j) {
                    double tmp = M[col][j]; M[col][j] = M[piv][j]; M[piv][j] = tmp;
                }
            const double inv = 1.0 / M[col][col];
            for (int r2 = col+1; r2 < 6; ++r2) {
                const double f = M[r2][col]*inv;
                for (int j = col; j < 7; ++j) M[r2][j] -= f*M[col][j];
            }
        }
        double xi[6];
        for (int i = 5; i >= 0; --i) {
            double s2 = M[i][6];
            for (int j = i+1; j < 6; ++j) s2 -= M[i][j]*xi[j];
            xi[i] = s2 / M[i][i];
        }
        double nxi[6];
        for (int i = 0; i < 6; ++i) nxi[i] = -xi[i];
        double E[16];
        se3_exp_d(nxi, E);

        double Tc[16];
        for (int k = 0; k < 16; ++k) Tc[k] = (double)Tcur[b*16+k];
        for (int i = 0; i < 4; ++i)
            for (int j = 0; j < 4; ++j) {
                double s2 = 0.0;
                for (int k = 0; k < 4; ++k) s2 += Tc[i*4+k]*E[k*4+j];
                const float f = (float)s2;
                Tcur[b*16 + i*4 + j] = f;
                out[b*16 + i*4 + j]  = f;
            }
    }
}

extern "C" void kernel_launch(void* const* d_in, const int* in_sizes, int n_in,
                              void* d_out, int out_size, void* d_ws, size_t ws_size,
                              hipStream_t stream) {
    const float* pose  = (const float*)d_in[0];
    const float* I0    = (const float*)d_in[1];
    const float* I1    = (const float*)d_in[2];
    const float* invD0 = (const float*)d_in[3];
    const float* invD1 = (const float*)d_in[4];
    const float* intr  = (const float*)d_in[5];
    float* out = (float*)d_out;

    float* Tcur     = (float*)d_ws;
    float* Tinit    = Tcur + 256;
    float* partials = (float*)((char*)d_ws + 2048);  // 16*112*27 floats ~ 189 KiB

    hipLaunchKernelGGL(init_kernel, dim3(1), dim3(64), 0, stream, pose, Tcur, Tinit);
    for (int it = 0; it < NITERS_; ++it) {
        hipLaunchKernelGGL(pixel_kernel, dim3(B_*BPB), dim3(TPB), 0, stream,
                           I0, I1, invD0, invD1, intr, Tcur, Tinit, partials);
        hipLaunchKernelGGL(solve_kernel, dim3(B_), dim3(64), 0, stream,
                           partials, Tcur, out);
    }
}